// Round 9
// baseline (838.306 us; speedup 1.0000x reference)
//
#include <hip/hip_runtime.h>
#include <hip/hip_bf16.h>
#include <cstdint>

// Problem constants
#define NB   2
#define NC   256
#define NN   4096   // H*W = 64*64
#define NH   8      // heads
#define HSZ  32     // head size
#define NF   256    // FEAT
#define N3F  768

typedef __bf16 bf16x8 __attribute__((ext_vector_type(8)));
typedef __bf16 bf16x4 __attribute__((ext_vector_type(4)));
typedef short  s16x4  __attribute__((ext_vector_type(4)));
typedef float  floatx4 __attribute__((ext_vector_type(4)));

// log2(e)/sqrt(32): folded into q so softmax runs in exp2 domain
#define QSCALE 0.25506601622184f

#define NBLK 1024

// Device-scope barrier: counter in global ws (zeroed by hipMemsetAsync each launch).
// Release: __threadfence (agent-scope, L2 writeback). Acquire: atomic load loop.
// Safe iff all NBLK blocks co-resident: __launch_bounds__(256,4) + 24KB LDS + grid
// 1024 = 4 blocks/CU x 256 CUs exactly (guide G1/G16 arithmetic).
__device__ __forceinline__ void gbar(int* cnt) {
    __syncthreads();
    if (threadIdx.x == 0) {
        __threadfence();
        atomicAdd(cnt, 1);
        while (__hip_atomic_load(cnt, __ATOMIC_ACQUIRE, __HIP_MEMORY_SCOPE_AGENT) < NBLK)
            __builtin_amdgcn_s_sleep(2);
        __threadfence();
    }
    __syncthreads();
}

__launch_bounds__(256, 4)
__global__ void k_mega(const float* __restrict__ x, const float* __restrict__ mm,
                       const float* __restrict__ mb, const float* __restrict__ wqkv,
                       const float* __restrict__ bqkv, const float* __restrict__ wproj,
                       const float* __restrict__ peqh, const float* __restrict__ peqw,
                       const float* __restrict__ pekh, const float* __restrict__ pekw,
                       const float* __restrict__ pab, const float* __restrict__ pqb,
                       const float* __restrict__ ppb, const float* __restrict__ idsc,
                       float* __restrict__ out, __bf16* __restrict__ y,
                       __bf16* __restrict__ qs, __bf16* __restrict__ kf,
                       __bf16* __restrict__ vf, __bf16* __restrict__ po,
                       float* __restrict__ pl, __bf16* __restrict__ wqb,
                       __bf16* __restrict__ wpb, int* __restrict__ bar) {
    __shared__ __align__(16) char smem_raw[24576];   // 24 KB union -> 4+ blocks/CU
    const int bi = blockIdx.x, tid = threadIdx.x;
    const int wave = tid >> 6, lane = tid & 63, ln = lane & 15, quad = lane >> 4;

    // ============ P0: preact silu (blocks 0..511) + weight cvt (512..767) =========
    if (bi < 512) {
        __bf16* ct = (__bf16*)smem_raw;            // [16][264]
        int b = bi >> 8, nt = bi & 255, n0 = nt * 16;
        int cbase = tid >> 2, nc = tid & 3;        // 64 c-lanes x 4 n-chunks (16 n)
#pragma unroll
        for (int q = 0; q < 4; q++) {
            int c = cbase + q * 64;
            const float4 xv = *(const float4*)(x + ((size_t)b * NC + c) * NN + n0 + nc * 4);
            float bias = pab[c], qb = pqb[c];
            float vs[4] = {xv.x, xv.y, xv.z, xv.w};
#pragma unroll
            for (int i = 0; i < 4; i++) {
                float s = vs[i] + bias;
                float r = s / (1.f + __expf(-s)) + qb;   // silu + pre_qkv_bias
                ct[(nc * 4 + i) * 264 + c] = (__bf16)r;
            }
        }
        __syncthreads();
#pragma unroll
        for (int q = 0; q < 2; q++) {
            int id = tid + q * 256;                // 512 chunks
            int n = id >> 5, ck = (id & 31) * 8;
            *(bf16x8*)(y + ((size_t)b * NN + n0 + n) * NC + ck) = *(const bf16x8*)(ct + n * 264 + ck);
        }
    } else if (bi < 768) {
        int id = (bi - 512) * 1024 + tid * 4;      // 262144 elems total
        const float* src = (id < 196608) ? (wqkv + id) : (wproj + (id - 196608));
        __bf16* dst = (id < 196608) ? (wqb + id) : (wpb + (id - 196608));
        float4 v = *(const float4*)src;
        bf16x4 o;
        o[0] = (__bf16)v.x; o[1] = (__bf16)v.y; o[2] = (__bf16)v.z; o[3] = (__bf16)v.w;
        *(bf16x4*)dst = o;
    }
    gbar(bar);

    // ============ P1: QKV GEMM, 64x64 tiles; 1536 tiles over 1024 blocks ==========
    {
        __bf16* smq = (__bf16*)smem_raw;           // 4 bufs of 2560 elems; ct alias
        __bf16* ct = smq;                          // 64*72 = 4608 elems
        for (int tt = 0; tt < 2; tt++) {
            int u = bi + tt * 1024;
            if (u >= 1536) break;
            if (tt) __syncthreads();
            const int nt = u & 63;
            const int rem = u >> 6;
            const int ot = rem % 12, b = rem / 12;
            const int wm = (wave & 1) * 32, wn = (wave >> 1) * 32;
            floatx4 acc[2][2];
#pragma unroll
            for (int i = 0; i < 2; i++)
#pragma unroll
                for (int j = 0; j < 2; j++) acc[i][j] = 0.f;
            const __bf16* ysrc = y + ((size_t)b * NN + nt * 64) * NC;
            const __bf16* wsrc = wqb + (size_t)ot * 64 * NC;
            const int r0 = tid >> 2, c0 = (tid & 3) * 8;
            bf16x8 ya = *(const bf16x8*)(ysrc + (size_t)r0 * NC + c0);
            bf16x8 wa = *(const bf16x8*)(wsrc + (size_t)r0 * NC + c0);
            for (int ko = 0; ko < 8; ko++) {
                int bo = (ko & 1) * 2560;
                *(bf16x8*)(smq + bo + r0 * 40 + c0) = ya;
                *(bf16x8*)(smq + 5120 + bo + r0 * 40 + c0) = wa;
                __syncthreads();
                if (ko < 7) {
                    int kc = (ko + 1) * 32;
                    ya = *(const bf16x8*)(ysrc + (size_t)r0 * NC + kc + c0);
                    wa = *(const bf16x8*)(wsrc + (size_t)r0 * NC + kc + c0);
                }
                bf16x8 af[2], bfr[2];
#pragma unroll
                for (int ii = 0; ii < 2; ii++) af[ii]  = *(const bf16x8*)(smq + bo + (wm + ii * 16 + ln) * 40 + quad * 8);
#pragma unroll
                for (int jj = 0; jj < 2; jj++) bfr[jj] = *(const bf16x8*)(smq + 5120 + bo + (wn + jj * 16 + ln) * 40 + quad * 8);
#pragma unroll
                for (int ii = 0; ii < 2; ii++)
#pragma unroll
                    for (int jj = 0; jj < 2; jj++)
                        acc[ii][jj] = __builtin_amdgcn_mfma_f32_16x16x32_bf16(af[ii], bfr[jj], acc[ii][jj], 0, 0, 0);
            }
            __syncthreads();   // frag reads done before ct alias written
            if (ot < 8) {
                // Q/K: ct[n_l][o_l]
#pragma unroll
                for (int ii = 0; ii < 2; ii++)
#pragma unroll
                    for (int jj = 0; jj < 2; jj++) {
                        int o_l = wn + jj * 16 + ln;
                        int o_g = ot * 64 + o_l;
                        float bq = bqkv[o_g];
#pragma unroll
                        for (int r = 0; r < 4; r++) {
                            int n_l = wm + ii * 16 + quad * 4 + r;
                            float val = acc[ii][jj][r] + bq;
                            if (ot < 4) {          // Q: PE + FiLM + softmax scale
                                val += peqh[o_g * 64 + nt] + peqw[o_g * 64 + n_l];
                                val = val * mm[b * NF + o_g] + mb[b * NF + o_g];
                                val *= QSCALE;
                            } else {               // K: PE
                                int c = o_g - 256;
                                val += pekh[c * 64 + nt] + pekw[c * 64 + n_l];
                            }
                            ct[n_l * 72 + o_l] = (__bf16)val;
                        }
                    }
                __syncthreads();
#pragma unroll
                for (int q = 0; q < 2; q++) {
                    int id = tid + q * 256;        // 512 chunks
                    int n_l = id >> 3, oc = (id & 7) * 8;
                    bf16x8 v = *(const bf16x8*)(ct + n_l * 72 + oc);
                    int n_g = nt * 64 + n_l;
                    int o_g = ot * 64 + oc;
                    if (ot < 4) {
                        int h = o_g >> 5, d = o_g & 31;
                        *(bf16x8*)(qs + (((size_t)b * NH + h) * NN + n_g) * HSZ + d) = v;
                    } else {
                        int c = o_g - 256, h = c >> 5, d0 = c & 31;
                        size_t blk = ((size_t)(b * NH + h) * 256 + (n_g >> 4)) * 512;
                        *(bf16x8*)(kf + blk + (d0 >> 3) * 128 + (n_g & 15) * 8) = v;
                    }
                }
            } else {
                // V: ct[o_l][n_l] -> vf fragment-major
#pragma unroll
                for (int ii = 0; ii < 2; ii++)
#pragma unroll
                    for (int jj = 0; jj < 2; jj++) {
                        int o_l = wn + jj * 16 + ln;
                        float bq = bqkv[ot * 64 + o_l];
#pragma unroll
                        for (int r = 0; r < 4; r++) {
                            int n_l = wm + ii * 16 + quad * 4 + r;
                            ct[o_l * 72 + n_l] = (__bf16)(acc[ii][jj][r] + bq);
                        }
                    }
                __syncthreads();
#pragma unroll
                for (int q = 0; q < 4; q++) {
                    int id = tid + q * 256;        // 1024 slots of 4 elems
                    int o_l = id >> 4, ng4 = (id & 15) * 4;
                    bf16x4 v = *(const bf16x4*)(ct + o_l * 72 + ng4);
                    int c = (ot - 8) * 64 + o_l, h = c >> 5, d = c & 31;
                    int dj = d >> 4, lnv = d & 15;
                    int m_g = nt * 64 + ng4;
                    size_t blk = ((size_t)(b * NH + h) * 256 + (m_g >> 4)) * 512;
                    *(bf16x4*)(vf + blk + (((m_g >> 2) & 3) * 16 + lnv) * 8 + dj * 4) = v;
                }
            }
        }
    }
    gbar(bar + 1);

    // ============ P2: flash attention (R7-proven 64q units, split-K x2) ===========
    {
        __bf16* sbuf = (__bf16*)smem_raw;          // 2 x 4096 elems = 16 KB
        for (int uu = 0; uu < 2; uu++) {
            int u = bi + uu * 1024;                // 2048 units; same bh/qt, halves
            int xcd = u & 7, r = u >> 3;
            int bh = xcd * 2 + (r & 1);
            int r2 = r >> 1;
            int qt = r2 & 63, half = r2 >> 6;
            if (uu) __syncthreads();
            int n0 = qt * 64 + wave * 16;
            const __bf16* qbase = qs + (size_t)bh * NN * HSZ;
            const __bf16* kfb = kf + ((size_t)bh * 256 + half * 128) * 512;
            const __bf16* vfb = vf + ((size_t)bh * 256 + half * 128) * 512;
            bf16x8 qa = *(const bf16x8*)(qbase + (size_t)(n0 + ln) * HSZ + quad * 8);
            floatx4 o[2], o2;
            o[0] = 0.f; o[1] = 0.f; o2 = 0.f;
            floatx4 zf = 0.f;
            s16x4 ones;
            ones[0] = (short)0x3F80; ones[1] = (short)0x3F80;
            ones[2] = (short)0x3F80; ones[3] = (short)0x3F80;   // bf16 1.0
            const int toff = tid * 8;
            const int lo = lane * 8;
            bf16x8 kr = *(const bf16x8*)(kfb + toff);
            bf16x8 vr = *(const bf16x8*)(vfb + toff);
            for (int mt = 0; mt < 32; mt++) {
                int bo = (mt & 1) << 12;
                *(bf16x8*)(sbuf + bo + toff) = kr;
                *(bf16x8*)(sbuf + bo + 2048 + toff) = vr;
                __syncthreads();                  // single barrier per tile
                if (mt < 31) {
                    kr = *(const bf16x8*)(kfb + (mt + 1) * 2048 + toff);
                    vr = *(const bf16x8*)(vfb + (mt + 1) * 2048 + toff);
                }
                const __bf16* kl = sbuf + bo;
                const __bf16* vl = sbuf + bo + 2048;
#pragma unroll
                for (int j = 0; j < 4; j++) {
                    bf16x8 kfr = *(const bf16x8*)(kl + j * 512 + lo);
                    bf16x8 vfr = *(const bf16x8*)(vl + j * 512 + lo);
                    s16x4 vb0, vb1;
                    __builtin_memcpy(&vb0, &vfr, 8);
                    __builtin_memcpy(&vb1, (const char*)&vfr + 8, 8);
                    floatx4 s = __builtin_amdgcn_mfma_f32_16x16x32_bf16(kfr, qa, zf, 0, 0, 0);
                    bf16x4 p;
#pragma unroll
                    for (int rr = 0; rr < 4; rr++)
                        p[rr] = (__bf16)__builtin_amdgcn_exp2f(s[rr]);
                    s16x4 pa;
                    __builtin_memcpy(&pa, &p, 8);
                    o[0] = __builtin_amdgcn_mfma_f32_16x16x16bf16_1k(pa, vb0, o[0], 0, 0, 0);
                    o[1] = __builtin_amdgcn_mfma_f32_16x16x16bf16_1k(pa, vb1, o[1], 0, 0, 0);
                    o2   = __builtin_amdgcn_mfma_f32_16x16x16bf16_1k(pa, ones, o2, 0, 0, 0);
                }
            }
            size_t plbase = (size_t)(half * 16 + bh) * NN;
            if (ln == 0)
#pragma unroll
                for (int rr = 0; rr < 4; rr++)
                    pl[plbase + n0 + quad * 4 + rr] = o2[rr];
            __bf16* ct = sbuf;                    // 64*32 elems (buf0; mt=31 used buf1)
#pragma unroll
            for (int dj = 0; dj < 2; dj++)
#pragma unroll
                for (int rr = 0; rr < 4; rr++)
                    ct[(wave * 16 + quad * 4 + rr) * 32 + dj * 16 + ln] = (__bf16)o[dj][rr];
            __syncthreads();
            size_t pobase = ((size_t)(half * 16 + bh) * NN + (size_t)qt * 64) * HSZ;
            {
                int n_l = tid >> 2, dc = (tid & 3) * 8;
                *(bf16x8*)(po + pobase + n_l * HSZ + dc) = *(const bf16x8*)(ct + n_l * 32 + dc);
            }
        }
    }
    gbar(bar + 2);

    // ============ P3: combine partials + proj GEMM + residual (blocks < 512) ======
    if (bi < 512) {
        __bf16* watd = (__bf16*)smem_raw;          // dbuf: +bo (2x2560 elems)
        __bf16* btd  = (__bf16*)smem_raw + 5120;   // dbuf: +bo
        float* linv = (float*)(smem_raw + 20480);  // 512 floats
        float* ppbs = (float*)(smem_raw + 22528);  // 256 floats
        const int nt = bi & 63, ot = (bi >> 6) & 3, b = bi >> 8;
        const int wo = (wave & 1) * 32, wn = (wave >> 1) * 32;
#pragma unroll
        for (int q = 0; q < 2; q++) {
            int id = tid + q * 256;                // 8h x 64n
            int h = id >> 6, n_l = id & 63;
            size_t base = (size_t)(b * NH + h) * NN + nt * 64 + n_l;
            linv[id] = 1.f / (pl[base] + pl[base + (size_t)16 * NN]);
        }
        ppbs[tid] = ppb[tid];
        floatx4 acc[2][2];
#pragma unroll
        for (int i = 0; i < 2; i++)
#pragma unroll
            for (int j = 0; j < 2; j++) acc[i][j] = 0.f;
        const int r0 = tid >> 2, c0 = (tid & 3) * 8;   // w row / f-chunk; also n_l / d-chunk
        const __bf16* wsrc = wpb + (size_t)ot * 64 * NF;
        const size_t hstep = (size_t)NN * HSZ;
        const size_t half_off = (size_t)16 * NN * HSZ;
        size_t prow = ((size_t)b * NH * NN + (size_t)nt * 64 + r0) * HSZ + c0;
        bf16x8 wa = *(const bf16x8*)(wsrc + (size_t)r0 * NF + c0);
        bf16x8 p0 = *(const bf16x8*)(po + prow);
        bf16x8 p1 = *(const bf16x8*)(po + prow + half_off);
        __syncthreads();                           // linv/ppbs visible
        for (int ko = 0; ko < 8; ko++) {
            int bo = (ko & 1) * 2560;
            *(bf16x8*)(watd + bo + r0 * 40 + c0) = wa;
            float iv = linv[ko * 64 + r0];
            bf16x8 c;
#pragma unroll
            for (int e = 0; e < 8; e++)
                c[e] = (__bf16)(((float)p0[e] + (float)p1[e]) * iv + ppbs[ko * 32 + c0 + e]);
            *(bf16x8*)(btd + bo + r0 * 40 + c0) = c;
            __syncthreads();
            if (ko < 7) {
                wa = *(const bf16x8*)(wsrc + (size_t)r0 * NF + (ko + 1) * 32 + c0);
                size_t pr = prow + (size_t)(ko + 1) * hstep;
                p0 = *(const bf16x8*)(po + pr);
                p1 = *(const bf16x8*)(po + pr + half_off);
            }
            bf16x8 af[2], bfr[2];
#pragma unroll
            for (int oi = 0; oi < 2; oi++) af[oi]  = *(const bf16x8*)(watd + bo + (wo + oi * 16 + ln) * 40 + quad * 8);
#pragma unroll
            for (int nj = 0; nj < 2; nj++) bfr[nj] = *(const bf16x8*)(btd + bo + (wn + nj * 16 + ln) * 40 + quad * 8);
#pragma unroll
            for (int oi = 0; oi < 2; oi++)
#pragma unroll
                for (int nj = 0; nj < 2; nj++)
                    acc[oi][nj] = __builtin_amdgcn_mfma_f32_16x16x32_bf16(af[oi], bfr[nj], acc[oi][nj], 0, 0, 0);
        }
#pragma unroll
        for (int oi = 0; oi < 2; oi++)
#pragma unroll
            for (int nj = 0; nj < 2; nj++)
#pragma unroll
                for (int r = 0; r < 4; r++) {
                    int o_g = ot * 64 + wo + oi * 16 + quad * 4 + r;
                    int n_g = nt * 64 + wn + nj * 16 + ln;
                    size_t idx = ((size_t)b * NF + o_g) * NN + n_g;
                    out[idx] = x[idx] * idsc[o_g] + acc[oi][nj][r];
                }
    }
}

// ---------------- launcher ----------------
extern "C" void kernel_launch(void* const* d_in, const int* in_sizes, int n_in,
                              void* d_out, int out_size, void* d_ws, size_t ws_size,
                              hipStream_t stream) {
    (void)in_sizes; (void)n_in; (void)out_size; (void)ws_size;
    const float* x    = (const float*)d_in[0];
    const float* mm   = (const float*)d_in[1];
    const float* mb   = (const float*)d_in[2];
    const float* wqkv = (const float*)d_in[3];
    const float* bqkv = (const float*)d_in[4];
    const float* wproj= (const float*)d_in[5];
    const float* peqh = (const float*)d_in[6];
    const float* peqw = (const float*)d_in[7];
    const float* pekh = (const float*)d_in[8];
    const float* pekw = (const float*)d_in[9];
    const float* pab  = (const float*)d_in[10];
    const float* pqb  = (const float*)d_in[11];
    const float* ppb  = (const float*)d_in[12];
    const float* idsc = (const float*)d_in[13];
    float* out = (float*)d_out;

    __bf16* ws = (__bf16*)d_ws;
    const size_t SEG = 2097152;            // elements per big buffer
    __bf16* y    = ws;
    __bf16* qs   = ws + SEG;
    __bf16* kf   = ws + SEG * 2;
    __bf16* vf   = ws + SEG * 3;
    __bf16* po   = ws + SEG * 4;           // 2 halves x 16bh x 4096 x 32 = 4M elems
    float*  pl   = (float*)(ws + SEG * 6); // 131072 floats
    __bf16* wqb  = ws + SEG * 6 + 262144;
    __bf16* wpb  = wqb + 196608;
    int*    bar  = (int*)(wpb + 65536);    // 3 barrier counters (zeroed below)

    hipMemsetAsync((void*)bar, 0, 64, stream);
    hipLaunchKernelGGL(k_mega, dim3(NBLK), dim3(256), 0, stream,
                       x, mm, mb, wqkv, bqkv, wproj, peqh, peqw, pekh, pekw,
                       pab, pqb, ppb, idsc, out, y, qs, kf, vf, po, pl, wqb, wpb, bar);
}